// Round 1
// baseline (180.403 us; speedup 1.0000x reference)
//
#include <hip/hip_runtime.h>
#include <math.h>

// Problem constants (from reference: N=512, D=4096, fp32).
#define PN 512
#define PD 4096
#define BK 32

// ws layout (floats):
//   [0,512)     sq_a[i]   = ||a_i||^2
//   [512,1024)  sq_p[j]   = ||p_j||^2
//   [1024,1536) dist_diag[i] = dist(a_i, p_i)
//   [1536]      global sum (float, atomic)
//   [1537]      global count (uint, atomic)

__global__ void taw_init_kernel(float* ws) {
    ws[1536] = 0.0f;
    ((unsigned int*)ws)[1537] = 0u;
}

__global__ __launch_bounds__(256) void taw_norms_kernel(
        const float* __restrict__ a, const float* __restrict__ p,
        float* __restrict__ ws) {
    const int i = blockIdx.x;
    const int t = threadIdx.x;
    const float4* a4 = (const float4*)(a + (size_t)i * PD);
    const float4* p4 = (const float4*)(p + (size_t)i * PD);
    float sa = 0.f, sp = 0.f, dp = 0.f;
#pragma unroll
    for (int c = 0; c < 4; ++c) {
        float4 av = a4[c * 256 + t];
        float4 pv = p4[c * 256 + t];
        sa += av.x * av.x + av.y * av.y + av.z * av.z + av.w * av.w;
        sp += pv.x * pv.x + pv.y * pv.y + pv.z * pv.z + pv.w * pv.w;
        dp += av.x * pv.x + av.y * pv.y + av.z * pv.z + av.w * pv.w;
    }
#pragma unroll
    for (int off = 32; off > 0; off >>= 1) {
        sa += __shfl_down(sa, off, 64);
        sp += __shfl_down(sp, off, 64);
        dp += __shfl_down(dp, off, 64);
    }
    __shared__ float red[3][4];
    const int wave = t >> 6;
    if ((t & 63) == 0) { red[0][wave] = sa; red[1][wave] = sp; red[2][wave] = dp; }
    __syncthreads();
    if (t == 0) {
        sa = red[0][0] + red[0][1] + red[0][2] + red[0][3];
        sp = red[1][0] + red[1][1] + red[1][2] + red[1][3];
        dp = red[2][0] + red[2][1] + red[2][2] + red[2][3];
        float d2 = sa - 2.f * dp + sp;
        d2 = fmaxf(d2, 0.f);
        float dist = (d2 == 0.f) ? 0.f : sqrtf(d2);
        ws[i] = sa;
        ws[512 + i] = sp;
        ws[1024 + i] = dist;
    }
}

// 32x32 output tile per block, 16x16 threads, 2x2 accum per thread, BK=32.
// Fused epilogue: d2 -> dist -> relu(diag - dist) -> block reduce -> atomics.
__global__ __launch_bounds__(256) void taw_gemm_loss_kernel(
        const float* __restrict__ A, const float* __restrict__ P,
        float* __restrict__ ws) {
    __shared__ float as[BK][34];  // [k][row], stride 34 floats (8B-aligned pairs)
    __shared__ float bs[BK][34];  // [k][col]
    const int tx = threadIdx.x;        // 0..15 -> cols
    const int ty = threadIdx.y;        // 0..15 -> rows
    const int t = ty * 16 + tx;
    const int i0 = blockIdx.y * 32;
    const int j0 = blockIdx.x * 32;

    // Staging: thread t loads 4 consecutive floats of row (t>>3), cols (t&7)*4.
    const int sr = t >> 3;
    const int sk = (t & 7) * 4;
    const float* aptr = A + (size_t)(i0 + sr) * PD + sk;
    const float* pptr = P + (size_t)(j0 + sr) * PD + sk;

    float c00 = 0.f, c01 = 0.f, c10 = 0.f, c11 = 0.f;

    for (int k0 = 0; k0 < PD; k0 += BK) {
        float4 av = *(const float4*)(aptr + k0);
        float4 pv = *(const float4*)(pptr + k0);
        __syncthreads();  // previous iter's reads done before overwrite
        as[sk + 0][sr] = av.x; as[sk + 1][sr] = av.y;
        as[sk + 2][sr] = av.z; as[sk + 3][sr] = av.w;
        bs[sk + 0][sr] = pv.x; bs[sk + 1][sr] = pv.y;
        bs[sk + 2][sr] = pv.z; bs[sk + 3][sr] = pv.w;
        __syncthreads();
#pragma unroll
        for (int kk = 0; kk < BK; ++kk) {
            const float2 a2 = *(const float2*)&as[kk][2 * ty];
            const float2 b2 = *(const float2*)&bs[kk][2 * tx];
            c00 = fmaf(a2.x, b2.x, c00);
            c01 = fmaf(a2.x, b2.y, c01);
            c10 = fmaf(a2.y, b2.x, c10);
            c11 = fmaf(a2.y, b2.y, c11);
        }
    }

    // Epilogue
    const float* sq_a = ws;
    const float* sq_p = ws + 512;
    const float* ddg  = ws + 1024;
    const int i = i0 + 2 * ty;
    const int j = j0 + 2 * tx;
    float cvals[2][2] = {{c00, c01}, {c10, c11}};
    float lsum = 0.f;
    unsigned int lcnt = 0;
#pragma unroll
    for (int dr = 0; dr < 2; ++dr) {
#pragma unroll
        for (int dc = 0; dc < 2; ++dc) {
            const int ii = i + dr, jj = j + dc;
            float d2 = sq_a[ii] - 2.f * cvals[dr][dc] + sq_p[jj];
            d2 = fmaxf(d2, 0.f);
            const float dist = (d2 == 0.f) ? 0.f : sqrtf(d2);
            const float v = (ii != jj) ? fmaxf(ddg[ii] - dist, 0.f) : 0.f;
            lsum += v;
            lcnt += (v > 1e-16f) ? 1u : 0u;
        }
    }
#pragma unroll
    for (int off = 32; off > 0; off >>= 1) {
        lsum += __shfl_down(lsum, off, 64);
        lcnt += __shfl_down(lcnt, off, 64);
    }
    __shared__ float rsum[4];
    __shared__ unsigned int rcnt[4];
    if ((t & 63) == 0) { rsum[t >> 6] = lsum; rcnt[t >> 6] = lcnt; }
    __syncthreads();
    if (t == 0) {
        const float bsum = rsum[0] + rsum[1] + rsum[2] + rsum[3];
        const unsigned int bcnt = rcnt[0] + rcnt[1] + rcnt[2] + rcnt[3];
        atomicAdd(ws + 1536, bsum);
        atomicAdd(((unsigned int*)ws) + 1537, bcnt);
    }
}

__global__ void taw_finalize_kernel(const float* __restrict__ ws,
                                    float* __restrict__ out) {
    const double s = (double)ws[1536];
    const double c = (double)(((const unsigned int*)ws)[1537]);
    out[0] = (float)(s / (c + 1e-16));
}

extern "C" void kernel_launch(void* const* d_in, const int* in_sizes, int n_in,
                              void* d_out, int out_size, void* d_ws, size_t ws_size,
                              hipStream_t stream) {
    (void)in_sizes; (void)n_in; (void)out_size; (void)ws_size;
    const float* a = (const float*)d_in[0];
    const float* p = (const float*)d_in[1];
    float* out = (float*)d_out;
    float* ws = (float*)d_ws;

    taw_init_kernel<<<1, 1, 0, stream>>>(ws);
    taw_norms_kernel<<<PN, 256, 0, stream>>>(a, p, ws);
    taw_gemm_loss_kernel<<<dim3(16, 16), dim3(16, 16), 0, stream>>>(a, p, ws);
    taw_finalize_kernel<<<1, 1, 0, stream>>>(ws, out);
}

// Round 2
// 111.777 us; speedup vs baseline: 1.6140x; 1.6140x over previous
//
#include <hip/hip_runtime.h>
#include <math.h>

// Problem constants (from reference: N=512, D=4096, fp32).
#define PN 512
#define PD 4096
#define KS 8           // split-K chunks
#define KCH (PD / KS)  // 512 k per chunk
#define BKS 16         // k-depth per LDS stage

// ws layout (floats):
//   [0,512)     sq_a[i]
//   [512,1024)  sq_p[j]
//   [1024,1536) dist_diag[i]
//   [1536]      global sum (float, atomic)
//   [1537]      global count (uint, atomic)
//   [2048, 2048 + 8*512*512)  split-K partial dot matrices
#define WS_PART_OFF 2048
#define WS_NEED ((size_t)(WS_PART_OFF + (size_t)KS * PN * PN) * 4)

// ---------------- norms (+ init of accumulators) ----------------
__global__ __launch_bounds__(256) void taw_norms_kernel(
        const float* __restrict__ a, const float* __restrict__ p,
        float* __restrict__ ws) {
    const int i = blockIdx.x;
    const int t = threadIdx.x;
    if (i == 0 && t == 0) {
        ws[1536] = 0.0f;
        ((unsigned int*)ws)[1537] = 0u;
    }
    const float4* a4 = (const float4*)(a + (size_t)i * PD);
    const float4* p4 = (const float4*)(p + (size_t)i * PD);
    float sa = 0.f, sp = 0.f, dp = 0.f;
#pragma unroll
    for (int c = 0; c < 4; ++c) {
        float4 av = a4[c * 256 + t];
        float4 pv = p4[c * 256 + t];
        sa += av.x * av.x + av.y * av.y + av.z * av.z + av.w * av.w;
        sp += pv.x * pv.x + pv.y * pv.y + pv.z * pv.z + pv.w * pv.w;
        dp += av.x * pv.x + av.y * pv.y + av.z * pv.z + av.w * pv.w;
    }
#pragma unroll
    for (int off = 32; off > 0; off >>= 1) {
        sa += __shfl_down(sa, off, 64);
        sp += __shfl_down(sp, off, 64);
        dp += __shfl_down(dp, off, 64);
    }
    __shared__ float red[3][4];
    const int wave = t >> 6;
    if ((t & 63) == 0) { red[0][wave] = sa; red[1][wave] = sp; red[2][wave] = dp; }
    __syncthreads();
    if (t == 0) {
        sa = red[0][0] + red[0][1] + red[0][2] + red[0][3];
        sp = red[1][0] + red[1][1] + red[1][2] + red[1][3];
        dp = red[2][0] + red[2][1] + red[2][2] + red[2][3];
        float d2 = sa - 2.f * dp + sp;
        d2 = fmaxf(d2, 0.f);
        float dist = (d2 == 0.f) ? 0.f : sqrtf(d2);
        ws[i] = sa;
        ws[512 + i] = sp;
        ws[1024 + i] = dist;
    }
}

// ---------------- split-K GEMM: 64x64 tile, K-chunk 512 ----------------
// grid (8, 8, KS), block (16,16). 4x4 accum/thread. Partials -> ws.
__global__ __launch_bounds__(256) void taw_gemm_part_kernel(
        const float* __restrict__ A, const float* __restrict__ P,
        float* __restrict__ ws) {
    __shared__ float as[BKS][68];  // [k][row], +4 pad
    __shared__ float bs[BKS][68];  // [k][col]
    const int tx = threadIdx.x;    // 0..15 -> col groups
    const int ty = threadIdx.y;    // 0..15 -> row groups
    const int t = ty * 16 + tx;
    const int i0 = blockIdx.y * 64;
    const int j0 = blockIdx.x * 64;
    const int kbase = blockIdx.z * KCH;

    // Staging: thread t loads float4 of row (t>>2), k offset (t&3)*4.
    const int sr = t >> 2;
    const int sk = (t & 3) * 4;
    const float* aptr = A + (size_t)(i0 + sr) * PD + kbase + sk;
    const float* pptr = P + (size_t)(j0 + sr) * PD + kbase + sk;

    float acc[4][4];
#pragma unroll
    for (int r = 0; r < 4; ++r)
#pragma unroll
        for (int c = 0; c < 4; ++c) acc[r][c] = 0.f;

    for (int k0 = 0; k0 < KCH / BKS; ++k0) {
        const float4 av = *(const float4*)(aptr + k0 * BKS);
        const float4 pv = *(const float4*)(pptr + k0 * BKS);
        __syncthreads();  // previous iter's LDS reads done
        as[sk + 0][sr] = av.x; as[sk + 1][sr] = av.y;
        as[sk + 2][sr] = av.z; as[sk + 3][sr] = av.w;
        bs[sk + 0][sr] = pv.x; bs[sk + 1][sr] = pv.y;
        bs[sk + 2][sr] = pv.z; bs[sk + 3][sr] = pv.w;
        __syncthreads();
#pragma unroll
        for (int kk = 0; kk < BKS; ++kk) {
            const float4 a4 = *(const float4*)&as[kk][4 * ty];
            const float4 b4 = *(const float4*)&bs[kk][4 * tx];
            const float ar[4] = {a4.x, a4.y, a4.z, a4.w};
            const float br[4] = {b4.x, b4.y, b4.z, b4.w};
#pragma unroll
            for (int r = 0; r < 4; ++r)
#pragma unroll
                for (int c = 0; c < 4; ++c)
                    acc[r][c] = fmaf(ar[r], br[c], acc[r][c]);
        }
    }

    float* part = ws + WS_PART_OFF + (size_t)blockIdx.z * (PN * PN);
#pragma unroll
    for (int r = 0; r < 4; ++r) {
        float4 v = {acc[r][0], acc[r][1], acc[r][2], acc[r][3]};
        *(float4*)(part + (size_t)(i0 + 4 * ty + r) * PN + j0 + 4 * tx) = v;
    }
}

// ---------------- reduce partials + epilogue ----------------
__global__ __launch_bounds__(256) void taw_reduce_kernel(float* __restrict__ ws) {
    const int g = blockIdx.x * 256 + threadIdx.x;  // 0..65535, 4 elems each
    const float4* part4 = (const float4*)(ws + WS_PART_OFF);
    float4 dot = part4[g];
#pragma unroll
    for (int ks = 1; ks < KS; ++ks) {
        const float4 v = part4[((size_t)ks << 16) + g];
        dot.x += v.x; dot.y += v.y; dot.z += v.z; dot.w += v.w;
    }
    const int flat = g << 2;
    const int i = flat >> 9;
    const int j = flat & 511;
    const float sa = ws[i];
    const float dd = ws[1024 + i];
    const float4 sp4 = *(const float4*)(ws + 512 + j);
    const float dotr[4] = {dot.x, dot.y, dot.z, dot.w};
    const float spr[4] = {sp4.x, sp4.y, sp4.z, sp4.w};
    float lsum = 0.f;
    unsigned int lcnt = 0;
#pragma unroll
    for (int c = 0; c < 4; ++c) {
        const int jj = j + c;
        float d2 = sa - 2.f * dotr[c] + spr[c];
        d2 = fmaxf(d2, 0.f);
        const float dist = (d2 == 0.f) ? 0.f : sqrtf(d2);
        const float v = (i != jj) ? fmaxf(dd - dist, 0.f) : 0.f;
        lsum += v;
        lcnt += (v > 1e-16f) ? 1u : 0u;
    }
#pragma unroll
    for (int off = 32; off > 0; off >>= 1) {
        lsum += __shfl_down(lsum, off, 64);
        lcnt += __shfl_down(lcnt, off, 64);
    }
    __shared__ float rsum[4];
    __shared__ unsigned int rcnt[4];
    const int t = threadIdx.x;
    if ((t & 63) == 0) { rsum[t >> 6] = lsum; rcnt[t >> 6] = lcnt; }
    __syncthreads();
    if (t == 0) {
        atomicAdd(ws + 1536, rsum[0] + rsum[1] + rsum[2] + rsum[3]);
        atomicAdd(((unsigned int*)ws) + 1537, rcnt[0] + rcnt[1] + rcnt[2] + rcnt[3]);
    }
}

__global__ void taw_finalize_kernel(const float* __restrict__ ws,
                                    float* __restrict__ out) {
    const double s = (double)ws[1536];
    const double c = (double)(((const unsigned int*)ws)[1537]);
    out[0] = (float)(s / (c + 1e-16));
}

// ---------------- fallback single-pass GEMM (Round-0 proven path) ----------------
__global__ __launch_bounds__(256) void taw_gemm_loss_kernel(
        const float* __restrict__ A, const float* __restrict__ P,
        float* __restrict__ ws) {
    __shared__ float as[32][34];
    __shared__ float bs[32][34];
    const int tx = threadIdx.x;
    const int ty = threadIdx.y;
    const int t = ty * 16 + tx;
    const int i0 = blockIdx.y * 32;
    const int j0 = blockIdx.x * 32;
    const int sr = t >> 3;
    const int sk = (t & 7) * 4;
    const float* aptr = A + (size_t)(i0 + sr) * PD + sk;
    const float* pptr = P + (size_t)(j0 + sr) * PD + sk;
    float c00 = 0.f, c01 = 0.f, c10 = 0.f, c11 = 0.f;
    for (int k0 = 0; k0 < PD; k0 += 32) {
        float4 av = *(const float4*)(aptr + k0);
        float4 pv = *(const float4*)(pptr + k0);
        __syncthreads();
        as[sk + 0][sr] = av.x; as[sk + 1][sr] = av.y;
        as[sk + 2][sr] = av.z; as[sk + 3][sr] = av.w;
        bs[sk + 0][sr] = pv.x; bs[sk + 1][sr] = pv.y;
        bs[sk + 2][sr] = pv.z; bs[sk + 3][sr] = pv.w;
        __syncthreads();
#pragma unroll
        for (int kk = 0; kk < 32; ++kk) {
            const float2 a2 = *(const float2*)&as[kk][2 * ty];
            const float2 b2 = *(const float2*)&bs[kk][2 * tx];
            c00 = fmaf(a2.x, b2.x, c00);
            c01 = fmaf(a2.x, b2.y, c01);
            c10 = fmaf(a2.y, b2.x, c10);
            c11 = fmaf(a2.y, b2.y, c11);
        }
    }
    const float* sq_a = ws;
    const float* sq_p = ws + 512;
    const float* ddg  = ws + 1024;
    const int i = i0 + 2 * ty;
    const int j = j0 + 2 * tx;
    float cvals[2][2] = {{c00, c01}, {c10, c11}};
    float lsum = 0.f;
    unsigned int lcnt = 0;
#pragma unroll
    for (int dr = 0; dr < 2; ++dr)
#pragma unroll
        for (int dc = 0; dc < 2; ++dc) {
            const int ii = i + dr, jj = j + dc;
            float d2 = sq_a[ii] - 2.f * cvals[dr][dc] + sq_p[jj];
            d2 = fmaxf(d2, 0.f);
            const float dist = (d2 == 0.f) ? 0.f : sqrtf(d2);
            const float v = (ii != jj) ? fmaxf(ddg[ii] - dist, 0.f) : 0.f;
            lsum += v;
            lcnt += (v > 1e-16f) ? 1u : 0u;
        }
#pragma unroll
    for (int off = 32; off > 0; off >>= 1) {
        lsum += __shfl_down(lsum, off, 64);
        lcnt += __shfl_down(lcnt, off, 64);
    }
    __shared__ float rsum[4];
    __shared__ unsigned int rcnt[4];
    if ((t & 63) == 0) { rsum[t >> 6] = lsum; rcnt[t >> 6] = lcnt; }
    __syncthreads();
    if (t == 0) {
        atomicAdd(ws + 1536, rsum[0] + rsum[1] + rsum[2] + rsum[3]);
        atomicAdd(((unsigned int*)ws) + 1537, rcnt[0] + rcnt[1] + rcnt[2] + rcnt[3]);
    }
}

extern "C" void kernel_launch(void* const* d_in, const int* in_sizes, int n_in,
                              void* d_out, int out_size, void* d_ws, size_t ws_size,
                              hipStream_t stream) {
    (void)in_sizes; (void)n_in; (void)out_size;
    const float* a = (const float*)d_in[0];
    const float* p = (const float*)d_in[1];
    float* out = (float*)d_out;
    float* ws = (float*)d_ws;

    taw_norms_kernel<<<PN, 256, 0, stream>>>(a, p, ws);
    if (ws_size >= WS_NEED) {
        taw_gemm_part_kernel<<<dim3(8, 8, KS), dim3(16, 16), 0, stream>>>(a, p, ws);
        taw_reduce_kernel<<<256, 256, 0, stream>>>(ws);
    } else {
        taw_gemm_loss_kernel<<<dim3(16, 16), dim3(16, 16), 0, stream>>>(a, p, ws);
    }
    taw_finalize_kernel<<<1, 1, 0, stream>>>(ws, out);
}

// Round 3
// 89.557 us; speedup vs baseline: 2.0144x; 1.2481x over previous
//
#include <hip/hip_runtime.h>
#include <math.h>

// Problem constants (from reference: N=512, D=4096, fp32).
#define PN 512
#define PD 4096

// bf16 MFMA split-K config
#define KSZ 8
#define KCHUNK (PD / KSZ)     // 512
#define BK 64                 // K per LDS stage
#define NSTAGE (KCHUNK / BK)  // 8

// ws layout (bytes):
//   [0,2048)    sa (512 f32)        float idx 0
//   [2048,4096) sp                  float idx 512
//   [4096,6144) dd (diag dist)      float idx 1024
//   [6144]      sum (f32 atomic)    float idx 1536
//   [6148]      cnt (u32 atomic)    float idx 1537
//   [8192, +4MB)        ah bf16 [512][4096]
//   [8192+4MB, +8MB)    ph bf16 [512][4096]
//   [8192+8MB, +8MB)    split-K partials f32 [KSZ][512][512]
#define WS_AH_BYTES 8192
#define WS_PH_BYTES (8192 + 4194304)
#define WS_PART_FLOAT 2099200                 // (8192 + 2*4194304)/4
#define WS_NEED_BF16 ((size_t)(8192 + 2 * 4194304 + (size_t)KSZ * PN * PN * 4))

typedef __attribute__((ext_vector_type(8))) short short8;
typedef __attribute__((ext_vector_type(4))) float floatx4;

static __device__ __forceinline__ unsigned short f2bf(float x) {
    // round-to-nearest-even fp32 -> bf16 (inputs are finite normals)
    unsigned int u = __float_as_uint(x);
    u += 0x7fffu + ((u >> 16) & 1u);
    return (unsigned short)(u >> 16);
}

static __device__ __forceinline__ void load16_lds(const void* gp, void* lp) {
    // 16B per lane, LDS dest = wave-uniform base + lane*16
    __builtin_amdgcn_global_load_lds(
        (const __attribute__((address_space(1))) unsigned int*)gp,
        (__attribute__((address_space(3))) unsigned int*)lp,
        16, 0, 0);
}

struct ushort4s { unsigned short x, y, z, w; };

// ---------------- prep: norms + diag dist + fp32->bf16 conversion ----------------
__global__ __launch_bounds__(256) void taw_prep_kernel(
        const float* __restrict__ a, const float* __restrict__ p,
        float* __restrict__ ws) {
    const int i = blockIdx.x;
    const int t = threadIdx.x;
    if (i == 0 && t == 0) {
        ws[1536] = 0.0f;
        ((unsigned int*)ws)[1537] = 0u;
    }
    const float4* a4 = (const float4*)(a + (size_t)i * PD);
    const float4* p4 = (const float4*)(p + (size_t)i * PD);
    unsigned short* ah = (unsigned short*)((char*)ws + WS_AH_BYTES) + (size_t)i * PD;
    unsigned short* ph = (unsigned short*)((char*)ws + WS_PH_BYTES) + (size_t)i * PD;
    float sa = 0.f, sp = 0.f, dp = 0.f;
#pragma unroll
    for (int c = 0; c < 4; ++c) {
        const int e = c * 256 + t;      // float4 index
        float4 av = a4[e];
        float4 pv = p4[e];
        sa += av.x * av.x + av.y * av.y + av.z * av.z + av.w * av.w;
        sp += pv.x * pv.x + pv.y * pv.y + pv.z * pv.z + pv.w * pv.w;
        dp += av.x * pv.x + av.y * pv.y + av.z * pv.z + av.w * pv.w;
        ushort4s ab = {f2bf(av.x), f2bf(av.y), f2bf(av.z), f2bf(av.w)};
        ushort4s pb = {f2bf(pv.x), f2bf(pv.y), f2bf(pv.z), f2bf(pv.w)};
        *(ushort4s*)(ah + (size_t)e * 4) = ab;
        *(ushort4s*)(ph + (size_t)e * 4) = pb;
    }
#pragma unroll
    for (int off = 32; off > 0; off >>= 1) {
        sa += __shfl_down(sa, off, 64);
        sp += __shfl_down(sp, off, 64);
        dp += __shfl_down(dp, off, 64);
    }
    __shared__ float red[3][4];
    const int wave = t >> 6;
    if ((t & 63) == 0) { red[0][wave] = sa; red[1][wave] = sp; red[2][wave] = dp; }
    __syncthreads();
    if (t == 0) {
        sa = red[0][0] + red[0][1] + red[0][2] + red[0][3];
        sp = red[1][0] + red[1][1] + red[1][2] + red[1][3];
        dp = red[2][0] + red[2][1] + red[2][2] + red[2][3];
        float d2 = sa - 2.f * dp + sp;
        d2 = fmaxf(d2, 0.f);
        ws[i] = sa;
        ws[512 + i] = sp;
        ws[1024 + i] = (d2 == 0.f) ? 0.f : sqrtf(d2);
    }
}

// ---------------- bf16 MFMA split-K GEMM: 64x64 tile, Kchunk 512 ----------------
// grid (8, 8, KSZ), block 256 (4 waves; wave w -> 32x32 quadrant (w>>1, w&1)).
// LDS in fragment order: lds[A/B][group g=s*4+rb][lane][8 bf16];
// group g holds rows rb*16+(lane&15), k-chunk s*4+(lane>>4) (8 bf16 each).
__global__ __launch_bounds__(256) void taw_mfma_kernel(float* __restrict__ ws) {
    __shared__ short lds[2][8][64][8];  // 16 KB
    const unsigned short* ah = (const unsigned short*)((const char*)ws + WS_AH_BYTES);
    const unsigned short* ph = (const unsigned short*)((const char*)ws + WS_PH_BYTES);
    const int t = threadIdx.x;
    const int lane = t & 63;
    const int w = t >> 6;
    const int wm = w >> 1, wn = w & 1;
    const int i0 = blockIdx.y * 64;
    const int j0 = blockIdx.x * 64;
    const int kz = blockIdx.z * KCHUNK;

    floatx4 acc[2][2] = {{{0.f, 0.f, 0.f, 0.f}, {0.f, 0.f, 0.f, 0.f}},
                         {{0.f, 0.f, 0.f, 0.f}, {0.f, 0.f, 0.f, 0.f}}};

    for (int st = 0; st < NSTAGE; ++st) {
        const int kb = kz + st * BK;
        __syncthreads();  // all ds_reads of previous stage done
#pragma unroll
        for (int q = 0; q < 2; ++q) {
            const int g = 2 * w + q;                       // wave w stages groups 2w, 2w+1
            const int row = ((g & 3) << 4) + (lane & 15);
            const int kk = kb + ((((g >> 2) << 2) + (lane >> 4)) << 3);
            load16_lds(ah + (size_t)(i0 + row) * PD + kk, &lds[0][g][0][0]);
            load16_lds(ph + (size_t)(j0 + row) * PD + kk, &lds[1][g][0][0]);
        }
        __syncthreads();  // drains vmcnt(0): staged data visible
#pragma unroll
        for (int s2 = 0; s2 < 2; ++s2) {
            short8 af0 = *(const short8*)&lds[0][s2 * 4 + wm * 2 + 0][lane][0];
            short8 af1 = *(const short8*)&lds[0][s2 * 4 + wm * 2 + 1][lane][0];
            short8 bf0 = *(const short8*)&lds[1][s2 * 4 + wn * 2 + 0][lane][0];
            short8 bf1 = *(const short8*)&lds[1][s2 * 4 + wn * 2 + 1][lane][0];
            acc[0][0] = __builtin_amdgcn_mfma_f32_16x16x32_bf16(af0, bf0, acc[0][0], 0, 0, 0);
            acc[0][1] = __builtin_amdgcn_mfma_f32_16x16x32_bf16(af0, bf1, acc[0][1], 0, 0, 0);
            acc[1][0] = __builtin_amdgcn_mfma_f32_16x16x32_bf16(af1, bf0, acc[1][0], 0, 0, 0);
            acc[1][1] = __builtin_amdgcn_mfma_f32_16x16x32_bf16(af1, bf1, acc[1][1], 0, 0, 0);
        }
    }

    // Partials: C/D layout col=lane&15, row=(lane>>4)*4+reg [m89-verified]
    float* part = ws + WS_PART_FLOAT + (size_t)blockIdx.z * (PN * PN);
    const int jj = j0 + wn * 32 + (lane & 15);
    const int ib = i0 + wm * 32 + ((lane >> 4) << 2);
#pragma unroll
    for (int rm = 0; rm < 2; ++rm)
#pragma unroll
        for (int rn = 0; rn < 2; ++rn)
#pragma unroll
            for (int r = 0; r < 4; ++r)
                part[(size_t)(ib + rm * 16 + r) * PN + jj + rn * 16] = acc[rm][rn][r];
}

// ---------------- reduce partials + epilogue ----------------
__global__ __launch_bounds__(256) void taw_reduce_kernel(float* __restrict__ ws) {
    const int g = blockIdx.x * 256 + threadIdx.x;  // 0..65535, one float4 each
    const float4* part4 = (const float4*)(ws + WS_PART_FLOAT);
    float4 dot = part4[g];
#pragma unroll
    for (int ks = 1; ks < KSZ; ++ks) {
        const float4 v = part4[((size_t)ks << 16) + g];
        dot.x += v.x; dot.y += v.y; dot.z += v.z; dot.w += v.w;
    }
    const int flat = g << 2;
    const int i = flat >> 9;
    const int j = flat & 511;
    const float sa = ws[i];
    const float dd = ws[1024 + i];
    const float4 sp4 = *(const float4*)(ws + 512 + j);
    const float dotr[4] = {dot.x, dot.y, dot.z, dot.w};
    const float spr[4] = {sp4.x, sp4.y, sp4.z, sp4.w};
    float lsum = 0.f;
    unsigned int lcnt = 0;
#pragma unroll
    for (int c = 0; c < 4; ++c) {
        const int jj = j + c;
        float d2 = sa - 2.f * dotr[c] + spr[c];
        d2 = fmaxf(d2, 0.f);
        const float dist = (d2 == 0.f) ? 0.f : sqrtf(d2);
        const float v = (i != jj) ? fmaxf(dd - dist, 0.f) : 0.f;
        lsum += v;
        lcnt += (v > 1e-16f) ? 1u : 0u;
    }
#pragma unroll
    for (int off = 32; off > 0; off >>= 1) {
        lsum += __shfl_down(lsum, off, 64);
        lcnt += __shfl_down(lcnt, off, 64);
    }
    __shared__ float rsum[4];
    __shared__ unsigned int rcnt[4];
    const int t = threadIdx.x;
    if ((t & 63) == 0) { rsum[t >> 6] = lsum; rcnt[t >> 6] = lcnt; }
    __syncthreads();
    if (t == 0) {
        atomicAdd(ws + 1536, rsum[0] + rsum[1] + rsum[2] + rsum[3]);
        atomicAdd(((unsigned int*)ws) + 1537, rcnt[0] + rcnt[1] + rcnt[2] + rcnt[3]);
    }
}

__global__ void taw_finalize_kernel(const float* __restrict__ ws,
                                    float* __restrict__ out) {
    const double s = (double)ws[1536];
    const double c = (double)(((const unsigned int*)ws)[1537]);
    out[0] = (float)(s / (c + 1e-16));
}

// ---------------- fallback single-pass fp32 GEMM (Round-0/1 proven path) ----------------
__global__ __launch_bounds__(256) void taw_gemm_loss_kernel(
        const float* __restrict__ A, const float* __restrict__ P,
        float* __restrict__ ws) {
    __shared__ float as[32][34];
    __shared__ float bs[32][34];
    const int tx = threadIdx.x;
    const int ty = threadIdx.y;
    const int t = ty * 16 + tx;
    const int i0 = blockIdx.y * 32;
    const int j0 = blockIdx.x * 32;
    const int sr = t >> 3;
    const int sk = (t & 7) * 4;
    const float* aptr = A + (size_t)(i0 + sr) * PD + sk;
    const float* pptr = P + (size_t)(j0 + sr) * PD + sk;
    float c00 = 0.f, c01 = 0.f, c10 = 0.f, c11 = 0.f;
    for (int k0 = 0; k0 < PD; k0 += 32) {
        float4 av = *(const float4*)(aptr + k0);
        float4 pv = *(const float4*)(pptr + k0);
        __syncthreads();
        as[sk + 0][sr] = av.x; as[sk + 1][sr] = av.y;
        as[sk + 2][sr] = av.z; as[sk + 3][sr] = av.w;
        bs[sk + 0][sr] = pv.x; bs[sk + 1][sr] = pv.y;
        bs[sk + 2][sr] = pv.z; bs[sk + 3][sr] = pv.w;
        __syncthreads();
#pragma unroll
        for (int kk = 0; kk < 32; ++kk) {
            const float2 a2 = *(const float2*)&as[kk][2 * ty];
            const float2 b2 = *(const float2*)&bs[kk][2 * tx];
            c00 = fmaf(a2.x, b2.x, c00);
            c01 = fmaf(a2.x, b2.y, c01);
            c10 = fmaf(a2.y, b2.x, c10);
            c11 = fmaf(a2.y, b2.y, c11);
        }
    }
    const float* sq_a = ws;
    const float* sq_p = ws + 512;
    const float* ddg  = ws + 1024;
    const int i = i0 + 2 * ty;
    const int j = j0 + 2 * tx;
    float cvals[2][2] = {{c00, c01}, {c10, c11}};
    float lsum = 0.f;
    unsigned int lcnt = 0;
#pragma unroll
    for (int dr = 0; dr < 2; ++dr)
#pragma unroll
        for (int dc = 0; dc < 2; ++dc) {
            const int ii = i + dr, jj = j + dc;
            float d2 = sq_a[ii] - 2.f * cvals[dr][dc] + sq_p[jj];
            d2 = fmaxf(d2, 0.f);
            const float dist = (d2 == 0.f) ? 0.f : sqrtf(d2);
            const float v = (ii != jj) ? fmaxf(ddg[ii] - dist, 0.f) : 0.f;
            lsum += v;
            lcnt += (v > 1e-16f) ? 1u : 0u;
        }
#pragma unroll
    for (int off = 32; off > 0; off >>= 1) {
        lsum += __shfl_down(lsum, off, 64);
        lcnt += __shfl_down(lcnt, off, 64);
    }
    __shared__ float rsum[4];
    __shared__ unsigned int rcnt[4];
    if ((t & 63) == 0) { rsum[t >> 6] = lsum; rcnt[t >> 6] = lcnt; }
    __syncthreads();
    if (t == 0) {
        atomicAdd(ws + 1536, rsum[0] + rsum[1] + rsum[2] + rsum[3]);
        atomicAdd(((unsigned int*)ws) + 1537, rcnt[0] + rcnt[1] + rcnt[2] + rcnt[3]);
    }
}

extern "C" void kernel_launch(void* const* d_in, const int* in_sizes, int n_in,
                              void* d_out, int out_size, void* d_ws, size_t ws_size,
                              hipStream_t stream) {
    (void)in_sizes; (void)n_in; (void)out_size;
    const float* a = (const float*)d_in[0];
    const float* p = (const float*)d_in[1];
    float* out = (float*)d_out;
    float* ws = (float*)d_ws;

    taw_prep_kernel<<<PN, 256, 0, stream>>>(a, p, ws);
    if (ws_size >= WS_NEED_BF16) {
        taw_mfma_kernel<<<dim3(8, 8, KSZ), 256, 0, stream>>>(ws);
        taw_reduce_kernel<<<256, 256, 0, stream>>>(ws);
    } else {
        taw_gemm_loss_kernel<<<dim3(16, 16), dim3(16, 16), 0, stream>>>(a, p, ws);
    }
    taw_finalize_kernel<<<1, 1, 0, stream>>>(ws, out);
}